// Round 1
// baseline (1596.015 us; speedup 1.0000x reference)
//
#include <hip/hip_runtime.h>

// GIN encoder: N=100k nodes, E=3.2M edges, G=512 graphs, H=64, L=3.
// Strategy: build CSR over dst once per launch, then per layer:
//   agg (CSR gather+sum, includes self) -> MLP (LDS weights) -> BN stats ->
//   BN finalize -> BN apply+ReLU. Finally segment-mean pool + output matmul.

#define HD 64

__global__ void count_deg(const int* __restrict__ dst, int* __restrict__ deg, int E) {
    int e = blockIdx.x * blockDim.x + threadIdx.x;
    if (e < E) atomicAdd(&deg[dst[e]], 1);
}

__global__ void scan_deg(const int* __restrict__ deg, int* __restrict__ rowstart,
                         int* __restrict__ cursor, int N) {
    __shared__ int sums[1024];
    int t = threadIdx.x;
    int chunk = (N + 1023) >> 10;
    int begin = t * chunk;
    int end = min(begin + chunk, N);
    int s = 0;
    for (int i = begin; i < end; i++) s += deg[i];
    sums[t] = s;
    __syncthreads();
    for (int off = 1; off < 1024; off <<= 1) {
        int v = (t >= off) ? sums[t - off] : 0;
        __syncthreads();
        sums[t] += v;
        __syncthreads();
    }
    int run = sums[t] - s;  // exclusive prefix of this thread's chunk
    for (int i = begin; i < end; i++) {
        int d = deg[i];
        rowstart[i] = run;
        cursor[i] = run;
        run += d;
    }
    if (t == 0) rowstart[N] = sums[1023];
}

__global__ void fill_csr(const int* __restrict__ src, const int* __restrict__ dst,
                         int* __restrict__ cursor, int* __restrict__ csr, int E) {
    int e = blockIdx.x * blockDim.x + threadIdx.x;
    if (e < E) {
        int d = dst[e];
        int p = atomicAdd(&cursor[d], 1);
        csr[p] = src[e];
    }
}

// Layer 0 aggregation: d=3, one thread per node. x is 1.2 MB -> cache-resident.
__global__ void agg3(const float* __restrict__ x, const int* __restrict__ rowstart,
                     const int* __restrict__ csr, float* __restrict__ out, int N) {
    int n = blockIdx.x * blockDim.x + threadIdx.x;
    if (n >= N) return;
    float a0 = x[n * 3], a1 = x[n * 3 + 1], a2 = x[n * 3 + 2];
    int s = rowstart[n], e = rowstart[n + 1];
    for (int j = s; j < e; j++) {
        int nb = csr[j];
        a0 += x[nb * 3];
        a1 += x[nb * 3 + 1];
        a2 += x[nb * 3 + 2];
    }
    out[n * 3] = a0;
    out[n * 3 + 1] = a1;
    out[n * 3 + 2] = a2;
}

// Layers 1-2 aggregation: 16 lanes per node, float4 per lane (64 floats/row).
__global__ void agg64(const float* __restrict__ x, const int* __restrict__ rowstart,
                      const int* __restrict__ csr, float* __restrict__ out, int N) {
    int g = threadIdx.x >> 4, l = threadIdx.x & 15;
    int n = blockIdx.x * 16 + g;
    if (n >= N) return;
    const float4* xr = (const float4*)x;
    float4 acc = xr[n * 16 + l];  // self term: h = x + agg
    int s = rowstart[n], e = rowstart[n + 1];
    for (int j = s; j < e; j++) {
        int nb = csr[j];
        float4 v = xr[nb * 16 + l];
        acc.x += v.x; acc.y += v.y; acc.z += v.z; acc.w += v.w;
    }
    ((float4*)out)[n * 16 + l] = acc;
}

// MLP: hout = relu(hin @ W1 + b1) @ W2 + b2.  16 threads/node x 4 outputs each.
__global__ __launch_bounds__(256) void mlp64(
    const float* __restrict__ hin, float* __restrict__ hout,
    const float* __restrict__ W1, const float* __restrict__ b1,
    const float* __restrict__ W2, const float* __restrict__ b2,
    int kin, int N) {
    __shared__ __align__(16) float w1s[64 * 64];
    __shared__ __align__(16) float w2s[64 * 64];
    __shared__ float b1s[64], b2s[64];
    __shared__ float hp[16][68];  // +4 pad: breaks 4-way write conflicts
    __shared__ float ts[16][68];
    int t = threadIdx.x;
    for (int i = t; i < kin * 64; i += 256) w1s[i] = W1[i];
    for (int i = t; i < 64 * 64; i += 256) w2s[i] = W2[i];
    if (t < 64) { b1s[t] = b1[t]; b2s[t] = b2[t]; }
    __syncthreads();
    int g = t >> 4, l = t & 15, f0 = l * 4;
    // N divisible by 16 -> every group has identical trip count (barriers uniform)
    for (int n = blockIdx.x * 16 + g; n < N; n += gridDim.x * 16) {
        for (int k = l; k < kin; k += 16) hp[g][k] = hin[n * kin + k];
        __syncthreads();
        float a0 = b1s[f0], a1 = b1s[f0 + 1], a2 = b1s[f0 + 2], a3 = b1s[f0 + 3];
        for (int k = 0; k < kin; k++) {
            float h = hp[g][k];
            float4 w = *(const float4*)&w1s[k * 64 + f0];
            a0 += h * w.x; a1 += h * w.y; a2 += h * w.z; a3 += h * w.w;
        }
        ts[g][f0] = fmaxf(a0, 0.f);
        ts[g][f0 + 1] = fmaxf(a1, 0.f);
        ts[g][f0 + 2] = fmaxf(a2, 0.f);
        ts[g][f0 + 3] = fmaxf(a3, 0.f);
        __syncthreads();
        a0 = b2s[f0]; a1 = b2s[f0 + 1]; a2 = b2s[f0 + 2]; a3 = b2s[f0 + 3];
        for (int k = 0; k < 64; k++) {
            float h = ts[g][k];
            float4 w = *(const float4*)&w2s[k * 64 + f0];
            a0 += h * w.x; a1 += h * w.y; a2 += h * w.z; a3 += h * w.w;
        }
        float4 o; o.x = a0; o.y = a1; o.z = a2; o.w = a3;
        ((float4*)hout)[n * 16 + l] = o;
        __syncthreads();  // protect hp/ts reuse across iterations
    }
}

// Column sums + sumsq for BN (biased batch stats).
__global__ void bn_stats(const float* __restrict__ h, float* __restrict__ bnsum,
                         float* __restrict__ bnsq, int N) {
    __shared__ float rs[256], rq[256];
    int t = threadIdx.x;
    int col = t & 63, ro = t >> 6;
    int rows_per = (N + gridDim.x - 1) / gridDim.x;
    int r0 = blockIdx.x * rows_per;
    int r1 = min(r0 + rows_per, N);
    float s = 0.f, q = 0.f;
    for (int r = r0 + ro; r < r1; r += 4) {
        float v = h[r * 64 + col];
        s += v;
        q += v * v;
    }
    rs[t] = s; rq[t] = q;
    __syncthreads();
    if (t < 64) {
        float S = rs[t] + rs[t + 64] + rs[t + 128] + rs[t + 192];
        float Q = rq[t] + rq[t + 64] + rq[t + 128] + rq[t + 192];
        atomicAdd(&bnsum[t], S);
        atomicAdd(&bnsq[t], Q);
    }
}

__global__ void bn_final(const float* __restrict__ bnsum, const float* __restrict__ bnsq,
                         const float* __restrict__ gamma, const float* __restrict__ beta,
                         float* __restrict__ scale, float* __restrict__ shift, int N) {
    int f = threadIdx.x;
    if (f < 64) {
        float mu = bnsum[f] / (float)N;
        float var = bnsq[f] / (float)N - mu * mu;
        float sc = gamma[f] * rsqrtf(var + 1e-5f);
        scale[f] = sc;
        shift[f] = beta[f] - mu * sc;
    }
}

// x = relu(h * scale + shift), in place, float4-vectorized.
__global__ void bn_apply(float* __restrict__ h, const float* __restrict__ scale,
                         const float* __restrict__ shift, int N) {
    int idx = blockIdx.x * blockDim.x + threadIdx.x;  // over N*16 float4
    if (idx >= N * 16) return;
    int f0 = (idx & 15) * 4;
    float4 v = ((float4*)h)[idx];
    v.x = fmaxf(v.x * scale[f0] + shift[f0], 0.f);
    v.y = fmaxf(v.y * scale[f0 + 1] + shift[f0 + 1], 0.f);
    v.z = fmaxf(v.z * scale[f0 + 2] + shift[f0 + 2], 0.f);
    v.w = fmaxf(v.w * scale[f0 + 3] + shift[f0 + 3], 0.f);
    ((float4*)h)[idx] = v;
}

__global__ void pool_kernel(const float* __restrict__ x, const int* __restrict__ batch,
                            float* __restrict__ pool, float* __restrict__ cnt, int N) {
    int g = threadIdx.x >> 4, l = threadIdx.x & 15;
    int n = blockIdx.x * 16 + g;
    if (n >= N) return;
    int b = batch[n];
    float4 v = ((const float4*)x)[n * 16 + l];
    atomicAdd(&pool[b * 64 + l * 4 + 0], v.x);
    atomicAdd(&pool[b * 64 + l * 4 + 1], v.y);
    atomicAdd(&pool[b * 64 + l * 4 + 2], v.z);
    atomicAdd(&pool[b * 64 + l * 4 + 3], v.w);
    if (l == 0) atomicAdd(&cnt[b], 1.0f);
}

__global__ void final_out(const float* __restrict__ pool, const float* __restrict__ cnt,
                          const float* __restrict__ wout, const float* __restrict__ bout,
                          float* __restrict__ out) {
    __shared__ float gr[64];
    int g = blockIdx.x, t = threadIdx.x;
    float c = cnt[g];
    float v = pool[g * 64 + t];
    gr[t] = (c > 0.f) ? v / fmaxf(c, 1.f) : 0.f;
    __syncthreads();
    float acc = bout[t];
    for (int f = 0; f < 64; f++) acc += gr[f] * wout[f * 64 + t];
    out[g * 64 + t] = acc;
}

extern "C" void kernel_launch(void* const* d_in, const int* in_sizes, int n_in,
                              void* d_out, int out_size, void* d_ws, size_t ws_size,
                              hipStream_t stream) {
    const float* x     = (const float*)d_in[0];
    const int*   ei    = (const int*)d_in[1];
    const int*   batch = (const int*)d_in[2];
    const float* w1_0  = (const float*)d_in[3];
    const float* w1_r  = (const float*)d_in[4];
    const float* b1    = (const float*)d_in[5];
    const float* w2    = (const float*)d_in[6];
    const float* b2    = (const float*)d_in[7];
    const float* gamma = (const float*)d_in[8];
    const float* beta  = (const float*)d_in[9];
    const float* wout  = (const float*)d_in[10];
    const float* bout  = (const float*)d_in[11];
    float* out = (float*)d_out;

    const int N = in_sizes[2];      // 100000
    const int E = in_sizes[1] / 2;  // 3200000
    const int G = out_size / HD;    // 512

    // Workspace layout (all fp32/int32, ~67 MB)
    float* bufA = (float*)d_ws;                     // N*64
    float* bufB = bufA + (size_t)N * 64;            // N*64
    float* h3   = bufB + (size_t)N * 64;            // N*3
    int* rowstart = (int*)(h3 + (size_t)N * 3);     // N+1
    int* cursor   = rowstart + (N + 1);             // N
    int* deg      = cursor + N;                     // N
    int* csr      = deg + N;                        // E
    float* bnsum  = (float*)(csr + E);              // 64
    float* bnsq   = bnsum + 64;                     // 64
    float* bnscale = bnsq + 64;                     // 64
    float* bnshift = bnscale + 64;                  // 64
    float* pool    = bnshift + 64;                  // G*64
    float* cnt     = pool + (size_t)G * 64;         // G

    const int* srcv = ei;
    const int* dstv = ei + E;

    // --- CSR build ---
    hipMemsetAsync(deg, 0, N * sizeof(int), stream);
    count_deg<<<(E + 255) / 256, 256, 0, stream>>>(dstv, deg, E);
    scan_deg<<<1, 1024, 0, stream>>>(deg, rowstart, cursor, N);
    fill_csr<<<(E + 255) / 256, 256, 0, stream>>>(srcv, dstv, cursor, csr, E);

    // --- Layer 0 (kin=3) ---
    agg3<<<(N + 255) / 256, 256, 0, stream>>>(x, rowstart, csr, h3, N);
    mlp64<<<1280, 256, 0, stream>>>(h3, bufA, w1_0, b1, w2, b2, 3, N);
    hipMemsetAsync(bnsum, 0, 128 * sizeof(float), stream);
    bn_stats<<<120, 256, 0, stream>>>(bufA, bnsum, bnsq, N);
    bn_final<<<1, 64, 0, stream>>>(bnsum, bnsq, gamma, beta, bnscale, bnshift, N);
    bn_apply<<<(N * 16 + 255) / 256, 256, 0, stream>>>(bufA, bnscale, bnshift, N);

    // --- Layers 1,2 (kin=64) ---
    for (int i = 1; i < 3; i++) {
        agg64<<<(N + 15) / 16, 256, 0, stream>>>(bufA, rowstart, csr, bufB, N);
        mlp64<<<1280, 256, 0, stream>>>(bufB, bufA, w1_r + (size_t)(i - 1) * 4096,
                                        b1 + i * 64, w2 + (size_t)i * 4096, b2 + i * 64, 64, N);
        hipMemsetAsync(bnsum, 0, 128 * sizeof(float), stream);
        bn_stats<<<120, 256, 0, stream>>>(bufA, bnsum, bnsq, N);
        bn_final<<<1, 64, 0, stream>>>(bnsum, bnsq, gamma + i * 64, beta + i * 64,
                                       bnscale, bnshift, N);
        bn_apply<<<(N * 16 + 255) / 256, 256, 0, stream>>>(bufA, bnscale, bnshift, N);
    }

    // --- Pool + output ---
    hipMemsetAsync(pool, 0, (G * 64 + G) * sizeof(float), stream);
    pool_kernel<<<(N + 15) / 16, 256, 0, stream>>>(bufA, batch, pool, cnt, N);
    final_out<<<G, 64, 0, stream>>>(pool, cnt, wout, bout, out);
}